// Round 2
// baseline (717.735 us; speedup 1.0000x reference)
//
#include <hip/hip_runtime.h>
#include <hip/hip_bf16.h>

// ModulePopHistory: per-item EMA over time prefix, gather at clip(time-1,0), sigmoid.
//   pop_history: [N, 128] float32 (row-major, 512 B/row = 4 x 128B lines)
//   time:        [N] int32
//   out:         [N] float32
// R1 post-mortem: input/output are fp32 (threshold = plain 2% rel, no bf16 floor;
// NaNs came from reinterpreting fp32 bits as bf16). Thread-per-item sequential
// EMA over just the needed prefix x[0..idx]; float4 (16B) chunk loads.

#define T_STEPS 128

__global__ __launch_bounds__(256) void ModulePopHistory_kernel(
    const float* __restrict__ pop,
    const int* __restrict__ timev,
    float* __restrict__ out,
    int n)
{
    int i = blockIdx.x * blockDim.x + threadIdx.x;
    if (i >= n) return;

    int idx = timev[i] - 1;
    if (idx < 0) idx = 0;
    if (idx > T_STEPS - 1) idx = T_STEPS - 1;

    const float4* row = (const float4*)(pop + (size_t)i * T_STEPS);
    int c_last = idx >> 2;        // chunk containing element idx
    int rem    = idx & 3;         // position of idx within that chunk

    // Chunk 0: ema starts at x[0].
    float4 w = row[0];
    float ema = w.x;
    if (c_last == 0) {
        if (rem >= 1) ema = fmaf(0.8f, ema, 0.2f * w.y);
        if (rem >= 2) ema = fmaf(0.8f, ema, 0.2f * w.z);
        if (rem >= 3) ema = fmaf(0.8f, ema, 0.2f * w.w);
    } else {
        ema = fmaf(0.8f, ema, 0.2f * w.y);
        ema = fmaf(0.8f, ema, 0.2f * w.z);
        ema = fmaf(0.8f, ema, 0.2f * w.w);

        // Full interior chunks.
        for (int c = 1; c < c_last; ++c) {
            float4 v = row[c];
            ema = fmaf(0.8f, ema, 0.2f * v.x);
            ema = fmaf(0.8f, ema, 0.2f * v.y);
            ema = fmaf(0.8f, ema, 0.2f * v.z);
            ema = fmaf(0.8f, ema, 0.2f * v.w);
        }

        // Final (possibly partial) chunk.
        float4 v = row[c_last];
        ema = fmaf(0.8f, ema, 0.2f * v.x);
        if (rem >= 1) ema = fmaf(0.8f, ema, 0.2f * v.y);
        if (rem >= 2) ema = fmaf(0.8f, ema, 0.2f * v.z);
        if (rem >= 3) ema = fmaf(0.8f, ema, 0.2f * v.w);
    }

    // sigmoid in fp32; ema in [0,1) so no range issues.
    float s = 1.0f / (1.0f + __expf(-ema));
    out[i] = s;
}

extern "C" void kernel_launch(void* const* d_in, const int* in_sizes, int n_in,
                              void* d_out, int out_size, void* d_ws, size_t ws_size,
                              hipStream_t stream) {
    const float* pop = (const float*)d_in[0];
    const int* timev = (const int*)d_in[1];
    // d_in[2] = item_id (unused by the reference output)
    float* out = (float*)d_out;

    int n = in_sizes[1];            // N_ITEMS (time vector length)
    const int block = 256;
    int grid = (n + block - 1) / block;
    hipLaunchKernelGGL(ModulePopHistory_kernel, dim3(grid), dim3(block), 0, stream,
                       pop, timev, out, n);
}